// Round 11
// baseline (409.245 us; speedup 1.0000x reference)
//
#include <hip/hip_runtime.h>
#include <math.h>

#define D_IN  128
#define D_HID 256
#define D_OUT 256
#define NXCD  8

typedef __attribute__((ext_vector_type(8))) short bf16x8;
typedef __attribute__((ext_vector_type(4))) float f32x4;
typedef __attribute__((ext_vector_type(2))) float f32x2;

__device__ __forceinline__ float bf2f(unsigned short u) {
    union { unsigned int i; float f; } v; v.i = ((unsigned int)u) << 16; return v.f;
}
__device__ __forceinline__ unsigned short f2bf(float f) {
    union { float f; unsigned int i; } v; v.f = f;
    unsigned int u = v.i;
    return (unsigned short)((u + 0x7FFFu + ((u >> 16) & 1u)) >> 16);
}
__device__ __forceinline__ float u2f(unsigned int u) {
    union { unsigned int i; float f; } v; v.i = u; return v.f;
}
// packed fp32 fma: acc = a*b + acc  (v_pk_fma_f32 — the 2x-fp32 path behind the 157 TF spec)
#define PK_FMA(acc, a, b) asm("v_pk_fma_f32 %0, %1, %2, %0" : "+v"(acc) : "v"(a), "v"(b))

#define GLOAD_LDS16(src, dst) \
    __builtin_amdgcn_global_load_lds((const __attribute__((address_space(1))) void*)(src), \
                                     (__attribute__((address_space(3))) void*)(dst), 16, 0, 0)

// ---------------------------------------------------------------- CSR build (XCD-partitioned hist/fill)
// blocks with (blockIdx.x & 7)==g land on XCD g (round-robin dispatch); group g owns rows
// [g*n/8,(g+1)*n/8) -> its deg/cursor/colout region stays in ONE L2 (R3->R4: fill write-amp fixed).
__global__ void hist_xcd(const int* __restrict__ r0, const int* __restrict__ r1, int E, int n,
                         int* __restrict__ d0, int* __restrict__ d1, int per) {
    const int* row = blockIdx.y ? r1 : r0;
    int* deg = blockIdx.y ? d1 : d0;
    const int g = blockIdx.x & (NXCD - 1);
    const int chunk = blockIdx.x >> 3;
    const int lo = g * (n >> 3);
    const int hi = (g == NXCD - 1) ? n : lo + (n >> 3);
    const int s = chunk * per, e = min(E, s + per);
    for (int i = s + (int)threadIdx.x; i < e; i += 256) {
        int r = row[i];
        if (r >= lo && r < hi) atomicAdd(&deg[r], 1);
    }
}

__global__ void fill_xcd(const int* __restrict__ r0, const int* __restrict__ c0,
                         const int* __restrict__ r1, const int* __restrict__ c1, int E, int n,
                         int* __restrict__ cu0, int* __restrict__ cu1,
                         int* __restrict__ o0, int* __restrict__ o1, int per) {
    const int* row = blockIdx.y ? r1 : r0;
    const int* colsrc = blockIdx.y ? c1 : c0;
    int* cursor = blockIdx.y ? cu1 : cu0;
    int* colout = blockIdx.y ? o1 : o0;
    const int g = blockIdx.x & (NXCD - 1);
    const int chunk = blockIdx.x >> 3;
    const int lo = g * (n >> 3);
    const int hi = (g == NXCD - 1) ? n : lo + (n >> 3);
    const int s = chunk * per, e = min(E, s + per);
    for (int i = s + (int)threadIdx.x; i < e; i += 256) {
        int r = row[i];
        if (r >= lo && r < hi) {
            int slot = atomicAdd(&cursor[r], 1);
            colout[slot] = colsrc[i];
        }
    }
}

__global__ void scan_partial2(const int* __restrict__ dg0, const int* __restrict__ dg1, int n,
                              int* __restrict__ p0, int* __restrict__ p1) {
    const int* deg = blockIdx.y ? dg1 : dg0;
    int* partial = blockIdx.y ? p1 : p0;
    __shared__ int sm[256];
    int i = blockIdx.x * 256 + threadIdx.x;
    sm[threadIdx.x] = (i < n) ? deg[i] : 0;
    __syncthreads();
    for (int off = 128; off > 0; off >>= 1) {
        if (threadIdx.x < off) sm[threadIdx.x] += sm[threadIdx.x + off];
        __syncthreads();
    }
    if (threadIdx.x == 0) partial[blockIdx.x] = sm[0];
}

__global__ void scan_top2(int* p0, int* p1, int nb) {
    int* partial = blockIdx.x ? p1 : p0;
    __shared__ int sm[256];
    int t = threadIdx.x;
    int orig = (t < nb) ? partial[t] : 0;
    sm[t] = orig;
    __syncthreads();
    for (int off = 1; off < 256; off <<= 1) {
        int v = (t >= off) ? sm[t - off] : 0;
        __syncthreads();
        sm[t] += v;
        __syncthreads();
    }
    if (t < nb) partial[t] = sm[t] - orig;   // exclusive prefix
}

__global__ void scan_final2(const int* __restrict__ dg0, const int* __restrict__ dg1,
                            const int* __restrict__ p0, const int* __restrict__ p1,
                            int n, int total,
                            int* __restrict__ rp0, int* __restrict__ rp1,
                            int* __restrict__ cu0, int* __restrict__ cu1) {
    const int* deg = blockIdx.y ? dg1 : dg0;
    const int* partial = blockIdx.y ? p1 : p0;
    int* rowptr = blockIdx.y ? rp1 : rp0;
    int* cursor = blockIdx.y ? cu1 : cu0;
    __shared__ int sm[256];
    int t = threadIdx.x;
    int i = blockIdx.x * 256 + t;
    int v = (i < n) ? deg[i] : 0;
    sm[t] = v;
    __syncthreads();
    for (int off = 1; off < 256; off <<= 1) {
        int u = (t >= off) ? sm[t - off] : 0;
        __syncthreads();
        sm[t] += u;
        __syncthreads();
    }
    int excl = sm[t] - v + partial[blockIdx.x];
    if (i < n) { rowptr[i] = excl; cursor[i] = excl; }
    if (i == n - 1) rowptr[n] = total;
}

// ---------------------------------------------------------------- conversions
__global__ void conv_x_kernel(const float* __restrict__ in, unsigned short* __restrict__ out, int n4) {
    int i = blockIdx.x * 256 + threadIdx.x;
    if (i < n4) {
        float4 v = ((const float4*)in)[i];
        ushort4 o;
        o.x = f2bf(v.x); o.y = f2bf(v.y); o.z = f2bf(v.z); o.w = f2bf(v.w);
        ((ushort4*)out)[i] = o;
    }
}

__global__ void conv_w_kernel(const float* w0, const float* w1, const float* w2, const float* w3,
                              const float* w4, const float* w5, const float* w6, const float* w7,
                              unsigned short* o0, unsigned short* o1, unsigned short* o2, unsigned short* o3,
                              unsigned short* o4, unsigned short* o5, unsigned short* o6, unsigned short* o7) {
    int m = blockIdx.y, c = blockIdx.x, k = threadIdx.x;
    const float* src; unsigned short* dst; int K;
    switch (m) {
        case 0: src = w0; dst = o0; K = 128; break;
        case 1: src = w1; dst = o1; K = 128; break;
        case 2: src = w2; dst = o2; K = 256; break;
        case 3: src = w3; dst = o3; K = 256; break;
        case 4: src = w4; dst = o4; K = 128; break;
        case 5: src = w5; dst = o5; K = 128; break;
        case 6: src = w6; dst = o6; K = 256; break;
        default: src = w7; dst = o7; K = 256; break;
    }
    if (k < K) dst[c * K + k] = f2bf(src[(size_t)k * 256 + c]);
}

// ---------------------------------------------------------------- L0 aggregation (bf16, 2 streams fused)
// bf16 unpack (shl/and) + v_pk_fma_f32 packed accumulate: 3 VALU/dword (was 4).
template<int D>
__global__ __launch_bounds__(256)
void agg3(const unsigned short* __restrict__ x0, const unsigned short* __restrict__ x1,
          const int* __restrict__ rp0, const int* __restrict__ ci0,
          const int* __restrict__ rp1, const int* __restrict__ ci1,
          unsigned short* __restrict__ n0, unsigned short* __restrict__ n1, int n) {
    const unsigned short* __restrict__ x = blockIdx.y ? x1 : x0;
    const int* __restrict__ rowptr = blockIdx.y ? rp1 : rp0;
    const int* __restrict__ colidx = blockIdx.y ? ci1 : ci0;
    unsigned short* __restrict__ nei = blockIdx.y ? n1 : n0;

    constexpr int RPW = (D == 256) ? 2 : 4;        // rows per wave-instruction
    constexpr int LPR = 64 / RPW;                  // lanes per row (32 or 16)
    const int wave = threadIdx.x >> 6, lane = threadIdx.x & 63;
    const int node = blockIdx.x * 4 + wave;
    if (node >= n) return;
    const int h = lane / LPR;                      // edge slot within group
    const int d = lane & (LPR - 1);                // 16B chunk within row

    const int s = rowptr[node], e = rowptr[node + 1];
    const float inv = 1.0f / ((float)(e - s) + 1e-12f);

    f32x2 acc[4] = {};                             // acc[q] = {elem 2q, elem 2q+1}
    if (s < e) {
        for (int j = s; j < e; j += 4 * RPW) {
            #pragma unroll
            for (int p = 0; p < 4; ++p) {
                int idx = j + p * RPW + h;
                float wgt = (idx < e) ? 1.0f : 0.0f;
                f32x2 w2; w2[0] = wgt; w2[1] = wgt;
                int c = colidx[idx < e ? idx : s];
                uint4 v = *(const uint4*)&x[(size_t)c * D + d * 8];
                #pragma unroll
                for (int q = 0; q < 4; ++q) {
                    unsigned int ww = (&v.x)[q];
                    f32x2 pv;
                    pv[0] = u2f(ww << 16);
                    pv[1] = u2f(ww & 0xFFFF0000u);
                    PK_FMA(acc[q], pv, w2);
                }
            }
        }
    }
    #pragma unroll
    for (int k = 0; k < 4; ++k) {
        if constexpr (RPW == 4) {
            acc[k][0] += __shfl_xor(acc[k][0], 16);
            acc[k][1] += __shfl_xor(acc[k][1], 16);
        }
        acc[k][0] += __shfl_xor(acc[k][0], 32);
        acc[k][1] += __shfl_xor(acc[k][1], 32);
    }
    if (h == 0) {
        uint4 o;
        o.x = (unsigned int)f2bf(acc[0][0] * inv) | ((unsigned int)f2bf(acc[0][1] * inv) << 16);
        o.y = (unsigned int)f2bf(acc[1][0] * inv) | ((unsigned int)f2bf(acc[1][1] * inv) << 16);
        o.z = (unsigned int)f2bf(acc[2][0] * inv) | ((unsigned int)f2bf(acc[2][1] * inv) << 16);
        o.w = (unsigned int)f2bf(acc[3][0] * inv) | ((unsigned int)f2bf(acc[3][1] * inv) << 16);
        *(uint4*)&nei[(size_t)node * D + d * 8] = o;
    }
}

// ---------------------------------------------------------------- L1 aggregation (uint8 gather)
// uint8 halves the 512B-row fabric traffic (R9: FETCH 353->164MB); v_cvt_f32_ubyteN dequant +
// v_pk_fma_f32 packed accumulate: 6 VALU/dword (was 8). Per-row float2 = (s_lo, s_hi) col-half scales.
template<int D>
__global__ __launch_bounds__(256)
void agg4(const unsigned char* __restrict__ t0, const unsigned char* __restrict__ t1,
          const float2* __restrict__ sm0, const float2* __restrict__ sm1,
          const int* __restrict__ rp0, const int* __restrict__ ci0,
          const int* __restrict__ rp1, const int* __restrict__ ci1,
          unsigned short* __restrict__ n0, unsigned short* __restrict__ n1, int n) {
    const unsigned char* __restrict__ tq = blockIdx.y ? t1 : t0;
    const float2* __restrict__ smp = blockIdx.y ? sm1 : sm0;
    const int* __restrict__ rowptr = blockIdx.y ? rp1 : rp0;
    const int* __restrict__ colidx = blockIdx.y ? ci1 : ci0;
    unsigned short* __restrict__ nei = blockIdx.y ? n1 : n0;

    constexpr int LPR = D / 16;                    // lanes per row (16B each)
    constexpr int RPW = 64 / LPR;                  // rows per wave-instruction
    constexpr int SLOTS = (D == 256) ? 4 : 2;      // load slots/iter
    const int wave = threadIdx.x >> 6, lane = threadIdx.x & 63;
    const int node = blockIdx.x * 4 + wave;
    if (node >= n) return;
    const int h = lane / LPR;
    const int chunk = lane & (LPR - 1);

    const int s = rowptr[node], e = rowptr[node + 1];
    const float inv = 1.0f / ((float)(e - s) + 1e-12f);

    f32x2 acc[8] = {};                             // acc[k] = {elem 2k, elem 2k+1}
    if (s < e) {
        for (int j = s; j < e; j += SLOTS * RPW) {
            #pragma unroll
            for (int p = 0; p < SLOTS; ++p) {
                int idx = j + p * RPW + h;
                bool in = idx < e;
                int c = colidx[in ? idx : s];
                float2 sm = smp[c];
                float s_ = (chunk < LPR / 2) ? sm.x : sm.y;
                float sw = in ? s_ : 0.f;
                f32x2 sw2; sw2[0] = sw; sw2[1] = sw;
                uint4 v = *(const uint4*)&tq[(size_t)c * D + chunk * 16];
                #pragma unroll
                for (int q = 0; q < 4; ++q) {
                    unsigned int ww = (&v.x)[q];
                    f32x2 lo, hi;
                    lo[0] = (float)(ww & 0xFFu);
                    lo[1] = (float)((ww >> 8) & 0xFFu);
                    hi[0] = (float)((ww >> 16) & 0xFFu);
                    hi[1] = (float)(ww >> 24);
                    PK_FMA(acc[q * 2 + 0], lo, sw2);
                    PK_FMA(acc[q * 2 + 1], hi, sw2);
                }
            }
        }
    }
    #pragma unroll
    for (int k = 0; k < 8; ++k) {
        #pragma unroll
        for (int off = LPR; off < 64; off <<= 1) {
            acc[k][0] += __shfl_xor(acc[k][0], off);
            acc[k][1] += __shfl_xor(acc[k][1], off);
        }
    }
    if (h == 0) {
        unsigned int out[8];
        #pragma unroll
        for (int k = 0; k < 8; ++k) {
            float a = acc[k][0] * inv;
            float b = acc[k][1] * inv;
            out[k] = (unsigned int)f2bf(a) | ((unsigned int)f2bf(b) << 16);
        }
        unsigned short* dst = nei + (size_t)node * D + chunk * 16;
        *(uint4*)dst = make_uint4(out[0], out[1], out[2], out[3]);
        *(uint4*)(dst + 8) = make_uint4(out[4], out[5], out[6], out[7]);
    }
}

// ---------------------------------------------------------------- MFMA GEMM (2-phase dbuf pipeline)
struct GemmArgs {
    const unsigned short* A0;
    const unsigned short* A1;
    const unsigned short* B0t;
    const unsigned short* B1t;
    const float* bias0;
    const float* bias1;
    void* out;
    unsigned char* qout;   // QUANT: uint8 activation gather table [M][256]
    float* scq;            // QUANT: per-row half scales [M*2] (col 0-127, 128-255)
};

// C[M,256] = epi( A0@W0 + A1@W1 + b0 + b1 ); blockIdx.z selects g0/g1
// MODE 0: bf16 out = relu(h);  MODE 1: fp32 out = w*extra + (1-w)*relu(h)
// QUANT: additionally emit uint8 quantized activations (LDS rowmax reduce per col-half).
template<int K, int MODE, bool QUANT>
__global__ __launch_bounds__(256)
void gemm_mfma(GemmArgs g0, GemmArgs g1, const unsigned short* __restrict__ extra,
               const float* __restrict__ alpha_p, int M) {
    constexpr int BK = 64;
    constexpr int NT = 2 * K / BK;                 // tiles across both operand pairs
    __shared__ unsigned short Asm[2][128 * BK];    // [128][64] row-major, 16B chunks XOR-swizzled
    __shared__ unsigned short Bsm[2][128 * BK];
    const GemmArgs g = blockIdx.z ? g1 : g0;
    const int t = threadIdx.x;
    const int l = t & 63, w = t >> 6;
    const int wr = w >> 1, wc = w & 1;             // 2x2 wave grid, 64x64 per wave
    const int row0 = blockIdx.x * 128;
    const int col0 = blockIdx.y * 128;

    const int seg = l >> 3;                        // row within 8-row segment
    const int src_chunk = (l & 7) ^ seg;           // inverse-swizzled source chunk

    f32x4 acc[4][4] = {};

    auto STAGE = [&](int tt, int buf) {
        const int op = tt >= (K / BK);
        const int k0 = (tt - op * (K / BK)) * BK;
        const unsigned short* __restrict__ A  = op ? g.A1  : g.A0;
        const unsigned short* __restrict__ Bt = op ? g.B1t : g.B0t;
        #pragma unroll
        for (int i = 0; i < 4; ++i) {
            const int rbase = w * 32 + i * 8;
            int grow = row0 + rbase + seg; if (grow > M - 1) grow = M - 1;
            GLOAD_LDS16(A + (size_t)grow * K + k0 + src_chunk * 8, &Asm[buf][rbase * 64]);
            GLOAD_LDS16(Bt + (size_t)(col0 + rbase + seg) * K + k0 + src_chunk * 8, &Bsm[buf][rbase * 64]);
        }
    };

    STAGE(0, 0);
    #pragma unroll
    for (int tt = 0; tt < NT; ++tt) {
        const int cur = tt & 1;
        if (tt + 1 < NT) {
            STAGE(tt + 1, cur ^ 1);
            asm volatile("s_waitcnt vmcnt(8)" ::: "memory");   // current buf's 8 loads done
        } else {
            asm volatile("s_waitcnt vmcnt(0)" ::: "memory");
        }
        __builtin_amdgcn_s_barrier();
        #pragma unroll
        for (int kk = 0; kk < 2; ++kk) {
            bf16x8 af[4], bfr[4];
            #pragma unroll
            for (int m = 0; m < 4; ++m) {
                int r = wr * 64 + m * 16 + (l & 15);
                int ch = (kk * 4 + (l >> 4)) ^ (r & 7);
                af[m] = *(const bf16x8*)&Asm[cur][r * 64 + ch * 8];
            }
            #pragma unroll
            for (int n = 0; n < 4; ++n) {
                int r = wc * 64 + n * 16 + (l & 15);
                int ch = (kk * 4 + (l >> 4)) ^ (r & 7);
                bfr[n] = *(const bf16x8*)&Bsm[cur][r * 64 + ch * 8];
            }
            #pragma unroll
            for (int m = 0; m < 4; ++m)
                #pragma unroll
                for (int n = 0; n < 4; ++n)
                    acc[m][n] = __builtin_amdgcn_mfma_f32_16x16x32_bf16(af[m], bfr[n], acc[m][n], 0, 0, 0);
        }
        asm volatile("s_waitcnt lgkmcnt(0)" ::: "memory");
        __builtin_amdgcn_s_barrier();
    }

    // ---- epilogue: row = row0+wr*64+m*16+(l>>4)*4+i, col = col0+wc*64+n*16+(l&15)
    float bsum[4];
    int cidx[4];
    #pragma unroll
    for (int n = 0; n < 4; ++n) {
        cidx[n] = col0 + wc * 64 + n * 16 + (l & 15);
        bsum[n] = g.bias0[cidx[n]] + g.bias1[cidx[n]];
    }
    float wmix = 0.f;
    if (MODE == 1) wmix = 1.0f / (1.0f + expf(-alpha_p[0]));

    int* rmaxI = (int*)Asm;                        // QUANT: 128 row maxima (LDS reuse, safe post-barrier)
    unsigned char* qt = (unsigned char*)Bsm;       // QUANT: 128x128 uint8 staging tile
    if constexpr (QUANT) {
        if (t < 128) rmaxI[t] = 0;
        __syncthreads();
    }

    #pragma unroll
    for (int m = 0; m < 4; ++m) {
        #pragma unroll
        for (int i = 0; i < 4; ++i) {
            int rloc = wr * 64 + m * 16 + (l >> 4) * 4 + i;
            int r = row0 + rloc;
            if (r >= M) continue;
            float mx = 0.f;
            #pragma unroll
            for (int n = 0; n < 4; ++n) {
                float h = acc[m][n][i] + bsum[n];
                float o = h > 0.f ? h : 0.f;
                mx = fmaxf(mx, o);
                if (MODE == 0) {
                    ((unsigned short*)g.out)[(size_t)r * 256 + cidx[n]] = f2bf(o);
                } else {
                    float ex = bf2f(extra[(size_t)r * 256 + cidx[n]]);
                    ((float*)g.out)[(size_t)r * 256 + cidx[n]] = wmix * ex + (1.f - wmix) * o;
                }
            }
            if constexpr (QUANT) atomicMax(&rmaxI[rloc], __float_as_int(mx));  // o >= 0: int cmp == float cmp
        }
    }

    if constexpr (QUANT) {
        __syncthreads();
        #pragma unroll
        for (int m = 0; m < 4; ++m) {
            #pragma unroll
            for (int i = 0; i < 4; ++i) {
                int rloc = wr * 64 + m * 16 + (l >> 4) * 4 + i;
                float rm = __int_as_float(rmaxI[rloc]);
                float invq = rm > 0.f ? 255.f / rm : 0.f;
                #pragma unroll
                for (int n = 0; n < 4; ++n) {
                    float h = acc[m][n][i] + bsum[n];
                    float o = h > 0.f ? h : 0.f;
                    qt[rloc * 128 + wc * 64 + n * 16 + (l & 15)] =
                        (unsigned char)fminf(255.f, fmaf(o, invq, 0.5f));
                }
                if (wc == 0 && (l & 15) == 0) {
                    int r = row0 + rloc;
                    if (r < M) g.scq[(size_t)r * 2 + blockIdx.y] = rm * (1.f / 255.f);
                }
            }
        }
        __syncthreads();
        // coalesced tile write-out: thread t -> row t>>1, 64B half-row
        int row = t >> 1, part = t & 1;
        int r = row0 + row;
        if (r < M) {
            #pragma unroll
            for (int k = 0; k < 4; ++k) {
                *(uint4*)&g.qout[(size_t)r * 256 + col0 + part * 64 + k * 16] =
                    *(const uint4*)&qt[row * 128 + part * 64 + k * 16];
            }
        }
    }
}

// ---------------------------------------------------------------- launch
extern "C" void kernel_launch(void* const* d_in, const int* in_sizes, int n_in,
                              void* d_out, int out_size, void* d_ws, size_t ws_size,
                              hipStream_t stream) {
    const float* x       = (const float*)d_in[0];
    const float* alpha_p = (const float*)d_in[1];
    const float* s0_ws = (const float*)d_in[2],  *s0_bs = (const float*)d_in[3];
    const float* s0_wn = (const float*)d_in[4],  *s0_bn = (const float*)d_in[5];
    const float* s1_ws = (const float*)d_in[6],  *s1_bs = (const float*)d_in[7];
    const float* s1_wn = (const float*)d_in[8],  *s1_bn = (const float*)d_in[9];
    const float* a0_ws = (const float*)d_in[10], *a0_bs = (const float*)d_in[11];
    const float* a0_wn = (const float*)d_in[12], *a0_bn = (const float*)d_in[13];
    const float* a1_ws = (const float*)d_in[14], *a1_bs = (const float*)d_in[15];
    const float* a1_wn = (const float*)d_in[16], *a1_bn = (const float*)d_in[17];
    const int* es = (const int*)d_in[18];   // [2,E]: row then col
    const int* ea = (const int*)d_in[19];

    const int N = in_sizes[0] / D_IN;
    const int E = in_sizes[18] / 2;
    const int* es_row = es, *es_col = es + E;
    const int* ea_row = ea, *ea_col = ea + E;

    // workspace carve-up (256B aligned)
    char* wsb = (char*)d_ws;
    size_t off = 0;
    auto carve = [&](size_t bytes) -> char* {
        char* p = wsb + off;
        off += (bytes + 255) & ~(size_t)255;
        return p;
    };
    unsigned short* xb     = (unsigned short*)carve((size_t)N * 128 * 2);   // x bf16
    unsigned short* neib_s = (unsigned short*)carve((size_t)N * 256 * 2);
    unsigned short* neib_a = (unsigned short*)carve((size_t)N * 256 * 2);
    unsigned short* actb_a = (unsigned short*)carve((size_t)N * 256 * 2);   // ha0 bf16
    unsigned short* actb_s = (unsigned short*)d_out;                        // hs0 bf16 (d_out scratch)
    // QBLOCK: uint8 act tables + scales, later ALIASED by hb (hs1 bf16).
    // Timeline: actq/scq written @gemmL0, read @aggL1; hb written @gemmL1s (after aggL1). No overlap.
    char* qblock = carve((size_t)2 * N * 256 + (size_t)2 * N * 8);
    unsigned char* actq_s = (unsigned char*)qblock;
    unsigned char* actq_a = actq_s + (size_t)N * 256;
    float* scq_s = (float*)(actq_a + (size_t)N * 256);
    float* scq_a = scq_s + (size_t)N * 2;
    unsigned short* hb = (unsigned short*)qblock;                           // hs1 bf16 (alias)
    unsigned short* wt[8];
    const int wK[8] = {128, 128, 256, 256, 128, 128, 256, 256};
    for (int i = 0; i < 8; ++i) wt[i] = (unsigned short*)carve((size_t)wK[i] * 256 * 2);
    int* deg      = (int*)carve((size_t)2 * N * 4);
    int* deg_s    = deg, *deg_a = deg + N;
    int* rowptr_s = (int*)carve((size_t)(N + 1) * 4);
    int* rowptr_a = (int*)carve((size_t)(N + 1) * 4);
    int* cur_s    = (int*)carve((size_t)N * 4);
    int* cur_a    = (int*)carve((size_t)N * 4);
    int* col_s    = (int*)carve((size_t)E * 4);
    int* col_a    = (int*)carve((size_t)E * 4);
    int* part_s   = (int*)carve(256 * 4);
    int* part_a   = (int*)carve(256 * 4);

    const int NB = (N + 255) / 256;
    const int NCHUNK = 128;                       // edge chunks per XCD group
    const int PER = (E + NCHUNK - 1) / NCHUNK;

    // ---- conversions
    conv_x_kernel<<<(N * 128 / 4 + 255) / 256, 256, 0, stream>>>(x, xb, N * 128 / 4);
    conv_w_kernel<<<dim3(256, 8), 256, 0, stream>>>(s0_ws, s0_wn, s1_ws, s1_wn,
                                                    a0_ws, a0_wn, a1_ws, a1_wn,
                                                    wt[0], wt[1], wt[2], wt[3],
                                                    wt[4], wt[5], wt[6], wt[7]);

    // ---- CSR build (both edge sets, XCD-partitioned hist/fill)
    hipMemsetAsync(deg, 0, (size_t)2 * N * 4, stream);
    hist_xcd<<<dim3(NCHUNK * NXCD, 2), 256, 0, stream>>>(es_row, ea_row, E, N, deg_s, deg_a, PER);
    scan_partial2<<<dim3(NB, 2), 256, 0, stream>>>(deg_s, deg_a, N, part_s, part_a);
    scan_top2<<<2, 256, 0, stream>>>(part_s, part_a, NB);
    scan_final2<<<dim3(NB, 2), 256, 0, stream>>>(deg_s, deg_a, part_s, part_a, N, E,
                                                 rowptr_s, rowptr_a, cur_s, cur_a);
    fill_xcd<<<dim3(NCHUNK * NXCD, 2), 256, 0, stream>>>(es_row, es_col, ea_row, ea_col, E, N,
                                                         cur_s, cur_a, col_s, col_a, PER);

    const int AGB = (N + 3) / 4;
    const int GMB = (N + 127) / 128;

    GemmArgs l0s = { xb, neib_s, wt[0], wt[1], s0_bs, s0_bn, actb_s, actq_s, scq_s };
    GemmArgs l0a = { xb, neib_a, wt[4], wt[5], a0_bs, a0_bn, actb_a, actq_a, scq_a };
    GemmArgs l1s = { actb_s, neib_s, wt[2], wt[3], s1_bs, s1_bn, hb, nullptr, nullptr };
    GemmArgs l1a = { actb_a, neib_a, wt[6], wt[7], a1_bs, a1_bn, d_out, nullptr, nullptr };

    // ---- layer 0: bf16 x-gather (both streams fused); GEMM emits bf16 act + uint8 act tables
    agg3<128><<<dim3(AGB, 2), 256, 0, stream>>>(xb, xb, rowptr_s, col_s, rowptr_a, col_a,
                                                neib_s, neib_a, N);
    gemm_mfma<128, 0, true><<<dim3(GMB, 2, 2), 256, 0, stream>>>(l0s, l0a, nullptr, alpha_p, N);

    // ---- layer 1: uint8 act-gather (fused), then GEMMs (hb aliases actq AFTER aggL1 reads it)
    agg4<256><<<dim3(AGB, 2), 256, 0, stream>>>(actq_s, actq_a, (const float2*)scq_s, (const float2*)scq_a,
                                                rowptr_s, col_s, rowptr_a, col_a,
                                                neib_s, neib_a, N);
    gemm_mfma<256, 0, false><<<dim3(GMB, 2, 1), 256, 0, stream>>>(l1s, l1s, nullptr, alpha_p, N);
    gemm_mfma<256, 1, false><<<dim3(GMB, 2, 1), 256, 0, stream>>>(l1a, l1a, hb, alpha_p, N);

    (void)n_in; (void)out_size; (void)ws_size;
}

// Round 12
// 371.392 us; speedup vs baseline: 1.1019x; 1.1019x over previous
//
#include <hip/hip_runtime.h>
#include <math.h>

#define D_IN  128
#define D_HID 256
#define D_OUT 256
#define NXCD  8

typedef __attribute__((ext_vector_type(8))) short bf16x8;
typedef __attribute__((ext_vector_type(4))) float f32x4;
typedef __attribute__((ext_vector_type(2))) float f32x2;

__device__ __forceinline__ float bf2f(unsigned short u) {
    union { unsigned int i; float f; } v; v.i = ((unsigned int)u) << 16; return v.f;
}
__device__ __forceinline__ unsigned short f2bf(float f) {
    union { float f; unsigned int i; } v; v.f = f;
    unsigned int u = v.i;
    return (unsigned short)((u + 0x7FFFu + ((u >> 16) & 1u)) >> 16);
}
__device__ __forceinline__ float u2f(unsigned int u) {
    union { unsigned int i; float f; } v; v.i = u; return v.f;
}

#define GLOAD_LDS16(src, dst) \
    __builtin_amdgcn_global_load_lds((const __attribute__((address_space(1))) void*)(src), \
                                     (__attribute__((address_space(3))) void*)(dst), 16, 0, 0)

// ---------------------------------------------------------------- CSR build (XCD-partitioned hist/fill)
// blocks with (blockIdx.x & 7)==g land on XCD g (round-robin dispatch); group g owns rows
// [g*n/8,(g+1)*n/8) -> its deg/cursor/colout region stays in ONE L2 (R3->R4: fill write-amp fixed).
__global__ void hist_xcd(const int* __restrict__ r0, const int* __restrict__ r1, int E, int n,
                         int* __restrict__ d0, int* __restrict__ d1, int per) {
    const int* row = blockIdx.y ? r1 : r0;
    int* deg = blockIdx.y ? d1 : d0;
    const int g = blockIdx.x & (NXCD - 1);
    const int chunk = blockIdx.x >> 3;
    const int lo = g * (n >> 3);
    const int hi = (g == NXCD - 1) ? n : lo + (n >> 3);
    const int s = chunk * per, e = min(E, s + per);
    for (int i = s + (int)threadIdx.x; i < e; i += 256) {
        int r = row[i];
        if (r >= lo && r < hi) atomicAdd(&deg[r], 1);
    }
}

__global__ void fill_xcd(const int* __restrict__ r0, const int* __restrict__ c0,
                         const int* __restrict__ r1, const int* __restrict__ c1, int E, int n,
                         int* __restrict__ cu0, int* __restrict__ cu1,
                         int* __restrict__ o0, int* __restrict__ o1, int per) {
    const int* row = blockIdx.y ? r1 : r0;
    const int* colsrc = blockIdx.y ? c1 : c0;
    int* cursor = blockIdx.y ? cu1 : cu0;
    int* colout = blockIdx.y ? o1 : o0;
    const int g = blockIdx.x & (NXCD - 1);
    const int chunk = blockIdx.x >> 3;
    const int lo = g * (n >> 3);
    const int hi = (g == NXCD - 1) ? n : lo + (n >> 3);
    const int s = chunk * per, e = min(E, s + per);
    for (int i = s + (int)threadIdx.x; i < e; i += 256) {
        int r = row[i];
        if (r >= lo && r < hi) {
            int slot = atomicAdd(&cursor[r], 1);
            colout[slot] = colsrc[i];
        }
    }
}

__global__ void scan_partial2(const int* __restrict__ dg0, const int* __restrict__ dg1, int n,
                              int* __restrict__ p0, int* __restrict__ p1) {
    const int* deg = blockIdx.y ? dg1 : dg0;
    int* partial = blockIdx.y ? p1 : p0;
    __shared__ int sm[256];
    int i = blockIdx.x * 256 + threadIdx.x;
    sm[threadIdx.x] = (i < n) ? deg[i] : 0;
    __syncthreads();
    for (int off = 128; off > 0; off >>= 1) {
        if (threadIdx.x < off) sm[threadIdx.x] += sm[threadIdx.x + off];
        __syncthreads();
    }
    if (threadIdx.x == 0) partial[blockIdx.x] = sm[0];
}

__global__ void scan_top2(int* p0, int* p1, int nb) {
    int* partial = blockIdx.x ? p1 : p0;
    __shared__ int sm[256];
    int t = threadIdx.x;
    int orig = (t < nb) ? partial[t] : 0;
    sm[t] = orig;
    __syncthreads();
    for (int off = 1; off < 256; off <<= 1) {
        int v = (t >= off) ? sm[t - off] : 0;
        __syncthreads();
        sm[t] += v;
        __syncthreads();
    }
    if (t < nb) partial[t] = sm[t] - orig;   // exclusive prefix
}

__global__ void scan_final2(const int* __restrict__ dg0, const int* __restrict__ dg1,
                            const int* __restrict__ p0, const int* __restrict__ p1,
                            int n, int total,
                            int* __restrict__ rp0, int* __restrict__ rp1,
                            int* __restrict__ cu0, int* __restrict__ cu1) {
    const int* deg = blockIdx.y ? dg1 : dg0;
    const int* partial = blockIdx.y ? p1 : p0;
    int* rowptr = blockIdx.y ? rp1 : rp0;
    int* cursor = blockIdx.y ? cu1 : cu0;
    __shared__ int sm[256];
    int t = threadIdx.x;
    int i = blockIdx.x * 256 + t;
    int v = (i < n) ? deg[i] : 0;
    sm[t] = v;
    __syncthreads();
    for (int off = 1; off < 256; off <<= 1) {
        int u = (t >= off) ? sm[t - off] : 0;
        __syncthreads();
        sm[t] += u;
        __syncthreads();
    }
    int excl = sm[t] - v + partial[blockIdx.x];
    if (i < n) { rowptr[i] = excl; cursor[i] = excl; }
    if (i == n - 1) rowptr[n] = total;
}

// ---------------------------------------------------------------- conversions
__global__ void conv_x_kernel(const float* __restrict__ in, unsigned short* __restrict__ out, int n4) {
    int i = blockIdx.x * 256 + threadIdx.x;
    if (i < n4) {
        float4 v = ((const float4*)in)[i];
        ushort4 o;
        o.x = f2bf(v.x); o.y = f2bf(v.y); o.z = f2bf(v.z); o.w = f2bf(v.w);
        ((ushort4*)out)[i] = o;
    }
}

__global__ void conv_w_kernel(const float* w0, const float* w1, const float* w2, const float* w3,
                              const float* w4, const float* w5, const float* w6, const float* w7,
                              unsigned short* o0, unsigned short* o1, unsigned short* o2, unsigned short* o3,
                              unsigned short* o4, unsigned short* o5, unsigned short* o6, unsigned short* o7) {
    int m = blockIdx.y, c = blockIdx.x, k = threadIdx.x;
    const float* src; unsigned short* dst; int K;
    switch (m) {
        case 0: src = w0; dst = o0; K = 128; break;
        case 1: src = w1; dst = o1; K = 128; break;
        case 2: src = w2; dst = o2; K = 256; break;
        case 3: src = w3; dst = o3; K = 256; break;
        case 4: src = w4; dst = o4; K = 128; break;
        case 5: src = w5; dst = o5; K = 128; break;
        case 6: src = w6; dst = o6; K = 256; break;
        default: src = w7; dst = o7; K = 256; break;
    }
    if (k < K) dst[c * K + k] = f2bf(src[(size_t)k * 256 + c]);
}

// ---------------------------------------------------------------- L0 aggregation (bf16, 2 streams fused)
// R10-proven scalar form (PK_FMA asm variant regressed via VGPR-pair pressure, R11).
template<int D>
__global__ __launch_bounds__(256)
void agg3(const unsigned short* __restrict__ x0, const unsigned short* __restrict__ x1,
          const int* __restrict__ rp0, const int* __restrict__ ci0,
          const int* __restrict__ rp1, const int* __restrict__ ci1,
          unsigned short* __restrict__ n0, unsigned short* __restrict__ n1, int n) {
    const unsigned short* __restrict__ x = blockIdx.y ? x1 : x0;
    const int* __restrict__ rowptr = blockIdx.y ? rp1 : rp0;
    const int* __restrict__ colidx = blockIdx.y ? ci1 : ci0;
    unsigned short* __restrict__ nei = blockIdx.y ? n1 : n0;

    constexpr int RPW = (D == 256) ? 2 : 4;        // rows per wave-instruction
    constexpr int LPR = 64 / RPW;                  // lanes per row (32 or 16)
    const int wave = threadIdx.x >> 6, lane = threadIdx.x & 63;
    const int node = blockIdx.x * 4 + wave;
    if (node >= n) return;
    const int h = lane / LPR;                      // edge slot within group
    const int d = lane & (LPR - 1);                // 16B chunk within row

    const int s = rowptr[node], e = rowptr[node + 1];
    const float inv = 1.0f / ((float)(e - s) + 1e-12f);

    float acc[8] = {};
    if (s < e) {
        for (int j = s; j < e; j += 4 * RPW) {
            #pragma unroll
            for (int p = 0; p < 4; ++p) {
                int idx = j + p * RPW + h;
                float wgt = (idx < e) ? 1.0f : 0.0f;
                int c = colidx[idx < e ? idx : s];
                uint4 v = *(const uint4*)&x[(size_t)c * D + d * 8];
                acc[0] = fmaf(wgt, u2f(v.x << 16), acc[0]);
                acc[1] = fmaf(wgt, u2f(v.x & 0xFFFF0000u), acc[1]);
                acc[2] = fmaf(wgt, u2f(v.y << 16), acc[2]);
                acc[3] = fmaf(wgt, u2f(v.y & 0xFFFF0000u), acc[3]);
                acc[4] = fmaf(wgt, u2f(v.z << 16), acc[4]);
                acc[5] = fmaf(wgt, u2f(v.z & 0xFFFF0000u), acc[5]);
                acc[6] = fmaf(wgt, u2f(v.w << 16), acc[6]);
                acc[7] = fmaf(wgt, u2f(v.w & 0xFFFF0000u), acc[7]);
            }
        }
    }
    #pragma unroll
    for (int k = 0; k < 8; ++k) {
        if constexpr (RPW == 4) acc[k] += __shfl_xor(acc[k], 16);
        acc[k] += __shfl_xor(acc[k], 32);
    }
    if (h == 0) {
        uint4 o;
        o.x = (unsigned int)f2bf(acc[0] * inv) | ((unsigned int)f2bf(acc[1] * inv) << 16);
        o.y = (unsigned int)f2bf(acc[2] * inv) | ((unsigned int)f2bf(acc[3] * inv) << 16);
        o.z = (unsigned int)f2bf(acc[4] * inv) | ((unsigned int)f2bf(acc[5] * inv) << 16);
        o.w = (unsigned int)f2bf(acc[6] * inv) | ((unsigned int)f2bf(acc[7] * inv) << 16);
        *(uint4*)&nei[(size_t)node * D + d * 8] = o;
    }
}

// ---------------------------------------------------------------- L1 aggregation (fp8-e4m3 gather)
// fp8 keeps uint8's traffic halving (R9: FETCH 353->164MB) but removes the per-neighbor scale
// gather + select entirely (fp8 has per-value exponent) and uses HW packed dequant
// (v_cvt_pk_f32_fp8: 2 elems/instr). 8B/lane (LPR=32, RPW=2) shrinks acc 16->8 floats and the
// cross-lane reduce 64->16 ops. Attacks R10's diagnosis: agg4 VALU-issue-bound (68% VALUBusy).
__global__ __launch_bounds__(256)
void agg5(const unsigned char* __restrict__ t0, const unsigned char* __restrict__ t1,
          const int* __restrict__ rp0, const int* __restrict__ ci0,
          const int* __restrict__ rp1, const int* __restrict__ ci1,
          unsigned short* __restrict__ n0, unsigned short* __restrict__ n1, int n) {
    const unsigned char* __restrict__ tq = blockIdx.y ? t1 : t0;
    const int* __restrict__ rowptr = blockIdx.y ? rp1 : rp0;
    const int* __restrict__ colidx = blockIdx.y ? ci1 : ci0;
    unsigned short* __restrict__ nei = blockIdx.y ? n1 : n0;

    const int wave = threadIdx.x >> 6, lane = threadIdx.x & 63;
    const int node = blockIdx.x * 4 + wave;
    if (node >= n) return;
    const int h = lane >> 5;                       // 2 rows per wave-instruction
    const int chunk = lane & 31;                   // 8B chunk within 256B row

    const int s = rowptr[node], e = rowptr[node + 1];
    const float inv = 1.0f / ((float)(e - s) + 1e-12f);

    float acc[8] = {};
    if (s < e) {
        for (int j = s; j < e; j += 16) {
            #pragma unroll
            for (int p = 0; p < 8; ++p) {
                int idx = j + p * 2 + h;
                bool in = idx < e;
                int c = colidx[in ? idx : s];
                uint2 v = *(const uint2*)&tq[(size_t)c * 256 + chunk * 8];
                unsigned int w0 = in ? v.x : 0u;   // fp8 0x00 == 0.0f
                unsigned int w1 = in ? v.y : 0u;
                f32x2 f0 = __builtin_amdgcn_cvt_pk_f32_fp8(w0, false);
                f32x2 f1 = __builtin_amdgcn_cvt_pk_f32_fp8(w0, true);
                f32x2 f2 = __builtin_amdgcn_cvt_pk_f32_fp8(w1, false);
                f32x2 f3 = __builtin_amdgcn_cvt_pk_f32_fp8(w1, true);
                acc[0] += f0[0]; acc[1] += f0[1]; acc[2] += f1[0]; acc[3] += f1[1];
                acc[4] += f2[0]; acc[5] += f2[1]; acc[6] += f3[0]; acc[7] += f3[1];
            }
        }
    }
    #pragma unroll
    for (int k = 0; k < 8; ++k) acc[k] += __shfl_xor(acc[k], 32);
    if (h == 0) {                                  // lanes 0-31 write one full 512B row
        unsigned int out[4];
        #pragma unroll
        for (int k = 0; k < 4; ++k)
            out[k] = (unsigned int)f2bf(acc[2 * k] * inv) |
                     ((unsigned int)f2bf(acc[2 * k + 1] * inv) << 16);
        *(uint4*)&nei[(size_t)node * 256 + chunk * 8] = make_uint4(out[0], out[1], out[2], out[3]);
    }
}

// ---------------------------------------------------------------- MFMA GEMM (2-phase dbuf pipeline)
struct GemmArgs {
    const unsigned short* A0;
    const unsigned short* A1;
    const unsigned short* B0t;
    const unsigned short* B1t;
    const float* bias0;
    const float* bias1;
    void* out;
    unsigned char* qout;   // QUANT: fp8-e4m3 activation gather table [M][256]
};

// C[M,256] = epi( A0@W0 + A1@W1 + b0 + b1 ); blockIdx.z selects g0/g1
// MODE 0: bf16 out = relu(h);  MODE 1: fp32 out = w*extra + (1-w)*relu(h)
// QUANT: additionally emit fp8-e4m3 activations (no scales -> no rowmax pass, cheaper than R10).
template<int K, int MODE, bool QUANT>
__global__ __launch_bounds__(256)
void gemm_mfma(GemmArgs g0, GemmArgs g1, const unsigned short* __restrict__ extra,
               const float* __restrict__ alpha_p, int M) {
    constexpr int BK = 64;
    constexpr int NT = 2 * K / BK;                 // tiles across both operand pairs
    __shared__ unsigned short Asm[2][128 * BK];    // [128][64] row-major, 16B chunks XOR-swizzled
    __shared__ unsigned short Bsm[2][128 * BK];
    const GemmArgs g = blockIdx.z ? g1 : g0;
    const int t = threadIdx.x;
    const int l = t & 63, w = t >> 6;
    const int wr = w >> 1, wc = w & 1;             // 2x2 wave grid, 64x64 per wave
    const int row0 = blockIdx.x * 128;
    const int col0 = blockIdx.y * 128;

    const int seg = l >> 3;                        // row within 8-row segment
    const int src_chunk = (l & 7) ^ seg;           // inverse-swizzled source chunk

    f32x4 acc[4][4] = {};

    auto STAGE = [&](int tt, int buf) {
        const int op = tt >= (K / BK);
        const int k0 = (tt - op * (K / BK)) * BK;
        const unsigned short* __restrict__ A  = op ? g.A1  : g.A0;
        const unsigned short* __restrict__ Bt = op ? g.B1t : g.B0t;
        #pragma unroll
        for (int i = 0; i < 4; ++i) {
            const int rbase = w * 32 + i * 8;
            int grow = row0 + rbase + seg; if (grow > M - 1) grow = M - 1;
            GLOAD_LDS16(A + (size_t)grow * K + k0 + src_chunk * 8, &Asm[buf][rbase * 64]);
            GLOAD_LDS16(Bt + (size_t)(col0 + rbase + seg) * K + k0 + src_chunk * 8, &Bsm[buf][rbase * 64]);
        }
    };

    STAGE(0, 0);
    #pragma unroll
    for (int tt = 0; tt < NT; ++tt) {
        const int cur = tt & 1;
        if (tt + 1 < NT) {
            STAGE(tt + 1, cur ^ 1);
            asm volatile("s_waitcnt vmcnt(8)" ::: "memory");   // current buf's 8 loads done
        } else {
            asm volatile("s_waitcnt vmcnt(0)" ::: "memory");
        }
        __builtin_amdgcn_s_barrier();
        #pragma unroll
        for (int kk = 0; kk < 2; ++kk) {
            bf16x8 af[4], bfr[4];
            #pragma unroll
            for (int m = 0; m < 4; ++m) {
                int r = wr * 64 + m * 16 + (l & 15);
                int ch = (kk * 4 + (l >> 4)) ^ (r & 7);
                af[m] = *(const bf16x8*)&Asm[cur][r * 64 + ch * 8];
            }
            #pragma unroll
            for (int n = 0; n < 4; ++n) {
                int r = wc * 64 + n * 16 + (l & 15);
                int ch = (kk * 4 + (l >> 4)) ^ (r & 7);
                bfr[n] = *(const bf16x8*)&Bsm[cur][r * 64 + ch * 8];
            }
            #pragma unroll
            for (int m = 0; m < 4; ++m)
                #pragma unroll
                for (int n = 0; n < 4; ++n)
                    acc[m][n] = __builtin_amdgcn_mfma_f32_16x16x32_bf16(af[m], bfr[n], acc[m][n], 0, 0, 0);
        }
        asm volatile("s_waitcnt lgkmcnt(0)" ::: "memory");
        __builtin_amdgcn_s_barrier();
    }

    // ---- epilogue: row = row0+wr*64+m*16+(l>>4)*4+i, col = col0+wc*64+n*16+(l&15)
    float bsum[4];
    int cidx[4];
    #pragma unroll
    for (int n = 0; n < 4; ++n) {
        cidx[n] = col0 + wc * 64 + n * 16 + (l & 15);
        bsum[n] = g.bias0[cidx[n]] + g.bias1[cidx[n]];
    }
    float wmix = 0.f;
    if (MODE == 1) wmix = 1.0f / (1.0f + expf(-alpha_p[0]));

    unsigned char* qt = (unsigned char*)Bsm;       // QUANT: 128x128 fp8 staging tile (safe post-barrier)

    #pragma unroll
    for (int m = 0; m < 4; ++m) {
        #pragma unroll
        for (int i = 0; i < 4; ++i) {
            int rloc = wr * 64 + m * 16 + (l >> 4) * 4 + i;
            int r = row0 + rloc;
            if (r >= M) continue;
            #pragma unroll
            for (int n = 0; n < 4; ++n) {
                float h = acc[m][n][i] + bsum[n];
                float o = h > 0.f ? h : 0.f;
                if (MODE == 0) {
                    ((unsigned short*)g.out)[(size_t)r * 256 + cidx[n]] = f2bf(o);
                } else {
                    float ex = bf2f(extra[(size_t)r * 256 + cidx[n]]);
                    ((float*)g.out)[(size_t)r * 256 + cidx[n]] = wmix * ex + (1.f - wmix) * o;
                }
                if constexpr (QUANT) {
                    int pk = __builtin_amdgcn_cvt_pk_fp8_f32(o, o, 0, false);
                    qt[rloc * 128 + wc * 64 + n * 16 + (l & 15)] = (unsigned char)(pk & 0xFF);
                }
            }
        }
    }

    if constexpr (QUANT) {
        __syncthreads();
        // coalesced tile write-out: thread t -> row t>>1, 64B half-row
        int row = t >> 1, part = t & 1;
        int r = row0 + row;
        if (r < M) {
            #pragma unroll
            for (int k = 0; k < 4; ++k) {
                *(uint4*)&g.qout[(size_t)r * 256 + col0 + part * 64 + k * 16] =
                    *(const uint4*)&qt[row * 128 + part * 64 + k * 16];
            }
        }
    }
}

// ---------------------------------------------------------------- launch
extern "C" void kernel_launch(void* const* d_in, const int* in_sizes, int n_in,
                              void* d_out, int out_size, void* d_ws, size_t ws_size,
                              hipStream_t stream) {
    const float* x       = (const float*)d_in[0];
    const float* alpha_p = (const float*)d_in[1];
    const float* s0_ws = (const float*)d_in[2],  *s0_bs = (const float*)d_in[3];
    const float* s0_wn = (const float*)d_in[4],  *s0_bn = (const float*)d_in[5];
    const float* s1_ws = (const float*)d_in[6],  *s1_bs = (const float*)d_in[7];
    const float* s1_wn = (const float*)d_in[8],  *s1_bn = (const float*)d_in[9];
    const float* a0_ws = (const float*)d_in[10], *a0_bs = (const float*)d_in[11];
    const float* a0_wn = (const float*)d_in[12], *a0_bn = (const float*)d_in[13];
    const float* a1_ws = (const float*)d_in[14], *a1_bs = (const float*)d_in[15];
    const float* a1_wn = (const float*)d_in[16], *a1_bn = (const float*)d_in[17];
    const int* es = (const int*)d_in[18];   // [2,E]: row then col
    const int* ea = (const int*)d_in[19];

    const int N = in_sizes[0] / D_IN;
    const int E = in_sizes[18] / 2;
    const int* es_row = es, *es_col = es + E;
    const int* ea_row = ea, *ea_col = ea + E;

    // workspace carve-up (256B aligned)
    char* wsb = (char*)d_ws;
    size_t off = 0;
    auto carve = [&](size_t bytes) -> char* {
        char* p = wsb + off;
        off += (bytes + 255) & ~(size_t)255;
        return p;
    };
    unsigned short* xb     = (unsigned short*)carve((size_t)N * 128 * 2);   // x bf16
    unsigned short* neib_s = (unsigned short*)carve((size_t)N * 256 * 2);
    unsigned short* neib_a = (unsigned short*)carve((size_t)N * 256 * 2);
    unsigned short* actb_a = (unsigned short*)carve((size_t)N * 256 * 2);   // ha0 bf16
    unsigned short* actb_s = (unsigned short*)d_out;                        // hs0 bf16 (d_out scratch)
    // QBLOCK: fp8 act tables, later ALIASED by hb (hs1 bf16).
    // Timeline: actq written @gemmL0, read @aggL1; hb written @gemmL1s (after aggL1). No overlap.
    char* qblock = carve((size_t)2 * N * 256);
    unsigned char* actq_s = (unsigned char*)qblock;
    unsigned char* actq_a = actq_s + (size_t)N * 256;
    unsigned short* hb = (unsigned short*)qblock;                           // hs1 bf16 (alias)
    unsigned short* wt[8];
    const int wK[8] = {128, 128, 256, 256, 128, 128, 256, 256};
    for (int i = 0; i < 8; ++i) wt[i] = (unsigned short*)carve((size_t)wK[i] * 256 * 2);
    int* deg      = (int*)carve((size_t)2 * N * 4);
    int* deg_s    = deg, *deg_a = deg + N;
    int* rowptr_s = (int*)carve((size_t)(N + 1) * 4);
    int* rowptr_a = (int*)carve((size_t)(N + 1) * 4);
    int* cur_s    = (int*)carve((size_t)N * 4);
    int* cur_a    = (int*)carve((size_t)N * 4);
    int* col_s    = (int*)carve((size_t)E * 4);
    int* col_a    = (int*)carve((size_t)E * 4);
    int* part_s   = (int*)carve(256 * 4);
    int* part_a   = (int*)carve(256 * 4);

    const int NB = (N + 255) / 256;
    const int NCHUNK = 128;                       // edge chunks per XCD group
    const int PER = (E + NCHUNK - 1) / NCHUNK;

    // ---- conversions
    conv_x_kernel<<<(N * 128 / 4 + 255) / 256, 256, 0, stream>>>(x, xb, N * 128 / 4);
    conv_w_kernel<<<dim3(256, 8), 256, 0, stream>>>(s0_ws, s0_wn, s1_ws, s1_wn,
                                                    a0_ws, a0_wn, a1_ws, a1_wn,
                                                    wt[0], wt[1], wt[2], wt[3],
                                                    wt[4], wt[5], wt[6], wt[7]);

    // ---- CSR build (both edge sets, XCD-partitioned hist/fill)
    hipMemsetAsync(deg, 0, (size_t)2 * N * 4, stream);
    hist_xcd<<<dim3(NCHUNK * NXCD, 2), 256, 0, stream>>>(es_row, ea_row, E, N, deg_s, deg_a, PER);
    scan_partial2<<<dim3(NB, 2), 256, 0, stream>>>(deg_s, deg_a, N, part_s, part_a);
    scan_top2<<<2, 256, 0, stream>>>(part_s, part_a, NB);
    scan_final2<<<dim3(NB, 2), 256, 0, stream>>>(deg_s, deg_a, part_s, part_a, N, E,
                                                 rowptr_s, rowptr_a, cur_s, cur_a);
    fill_xcd<<<dim3(NCHUNK * NXCD, 2), 256, 0, stream>>>(es_row, es_col, ea_row, ea_col, E, N,
                                                         cur_s, cur_a, col_s, col_a, PER);

    const int AGB = (N + 3) / 4;
    const int GMB = (N + 127) / 128;

    GemmArgs l0s = { xb, neib_s, wt[0], wt[1], s0_bs, s0_bn, actb_s, actq_s };
    GemmArgs l0a = { xb, neib_a, wt[4], wt[5], a0_bs, a0_bn, actb_a, actq_a };
    GemmArgs l1s = { actb_s, neib_s, wt[2], wt[3], s1_bs, s1_bn, hb, nullptr };
    GemmArgs l1a = { actb_a, neib_a, wt[6], wt[7], a1_bs, a1_bn, d_out, nullptr };

    // ---- layer 0: bf16 x-gather (both streams fused); GEMM emits bf16 act + fp8 act tables
    agg3<128><<<dim3(AGB, 2), 256, 0, stream>>>(xb, xb, rowptr_s, col_s, rowptr_a, col_a,
                                                neib_s, neib_a, N);
    gemm_mfma<128, 0, true><<<dim3(GMB, 2, 2), 256, 0, stream>>>(l0s, l0a, nullptr, alpha_p, N);

    // ---- layer 1: fp8 act-gather (fused), then GEMMs (hb aliases actq AFTER aggL1 reads it)
    agg5<<<dim3(AGB, 2), 256, 0, stream>>>(actq_s, actq_a,
                                           rowptr_s, col_s, rowptr_a, col_a,
                                           neib_s, neib_a, N);
    gemm_mfma<256, 0, false><<<dim3(GMB, 2, 1), 256, 0, stream>>>(l1s, l1s, nullptr, alpha_p, N);
    gemm_mfma<256, 1, false><<<dim3(GMB, 2, 1), 256, 0, stream>>>(l1a, l1a, hb, alpha_p, N);

    (void)n_in; (void)out_size; (void)ws_size;
}